// Round 3
// baseline (277.769 us; speedup 1.0000x reference)
//
#include <hip/hip_runtime.h>

#define D_DIM 8192
#define BK 128
#define SPLITK 8
#define KS (D_DIM / SPLITK)      // 1024 per slice
#define NCHUNK (KS / BK)         // 8
#define BN 32
#define NTILE 320

typedef float f32x4 __attribute__((ext_vector_type(4)));
typedef short s16x8 __attribute__((ext_vector_type(8)));
typedef short s16x4 __attribute__((ext_vector_type(4)));

__device__ __forceinline__ unsigned short f2bf(float f) {
  union { float f; unsigned u; } v; v.f = f;
  return (unsigned short)((v.u + 0x7FFFu + ((v.u >> 16) & 1u)) >> 16);
}

// Stage one BK-chunk of x (32 batches) and W (32 rows) into registers.
// Flat float4 index f = tid + t*256: row = f>>5, col4 = f&31 (BK/4 = 32).
#define ISSUE_LOADS(XS, WS, CH) do {                                            \
    const int k0_ = kbase + (CH) * BK;                                          \
    _Pragma("unroll")                                                           \
    for (int t = 0; t < 4; ++t) {                                               \
      const int f_ = tid + t * 256;                                             \
      const int r_ = f_ >> 5, c4_ = f_ & 31;                                    \
      XS[t] = *reinterpret_cast<const f32x4*>(                                  \
          x + (size_t)r_ * D_DIM + k0_ + c4_ * 4);                              \
      WS[t] = *reinterpret_cast<const f32x4*>(                                  \
          wptr + (size_t)(erow0 + r_) * D_DIM + k0_ + c4_ * 4);                 \
    } } while (0)

// Convert staged fp32 -> bf16 and write swizzled LDS buffer BUF.
#define CVT_WRITE(XS, WS, BUF) do {                                             \
    _Pragma("unroll")                                                           \
    for (int t = 0; t < 4; ++t) {                                               \
      const int f_ = tid + t * 256;                                             \
      const int r_ = f_ >> 5, c4_ = f_ & 31;                                    \
      const int sc_ = (c4_ * 4) ^ ((r_ & 7) << 3);                              \
      s16x4 xv_, wv_;                                                           \
      _Pragma("unroll")                                                         \
      for (int j = 0; j < 4; ++j) {                                             \
        xv_[j] = (short)f2bf(XS[t][j]);                                         \
        wv_[j] = (short)f2bf(WS[t][j]);                                         \
      }                                                                         \
      *reinterpret_cast<s16x4*>(&lds[BUF][0][r_ * BK + sc_]) = xv_;             \
      *reinterpret_cast<s16x4*>(&lds[BUF][1][r_ * BK + sc_]) = wv_;             \
    } } while (0)

// 4 K-steps of 32: read A/B fragments (swizzled) and MFMA.
#define MFMA_STEP(BUF) do {                                                     \
    _Pragma("unroll")                                                           \
    for (int ks = 0; ks < 4; ++ks) {                                            \
      const int ce_ = ks * 32 + kg;                                             \
      s16x8 av_ = *reinterpret_cast<const s16x8*>(                              \
          &lds[BUF][0][arow * BK + (ce_ ^ axor)]);                              \
      s16x8 bv_ = *reinterpret_cast<const s16x8*>(                              \
          &lds[BUF][1][brow * BK + (ce_ ^ bxor)]);                              \
      acc = __builtin_amdgcn_mfma_f32_16x16x32_bf16(av_, bv_, acc, 0, 0, 0);    \
    } } while (0)

template <int WRITE_MODE>  // 0 = workspace partials, 1 = atomic to out
__global__ __launch_bounds__(256, 5) void qkv_gemm(
    const float* __restrict__ x, const float* __restrict__ wq,
    const float* __restrict__ wk, const float* __restrict__ wv,
    float* __restrict__ ws_out, float* __restrict__ out)
{
  // [buf][0=x / 1=w][row * BK + col], bf16 as ushort.  2*2*32*128*2B = 32 KiB
  __shared__ unsigned short lds[2][2][BN * BK];

  const int bid    = blockIdx.x;
  const int tile   = bid >> 3;       // 0..319
  const int kslice = bid & 7;        // 0..7
  const int kbase  = kslice * KS;

  const int e0 = tile * BN;
  const float* wptr;
  int outbase, erow0;
  if (e0 < 8192)      { wptr = wq; outbase = 0;      erow0 = e0; }
  else if (e0 < 9216) { wptr = wk; outbase = 262144; erow0 = e0 - 8192; }
  else                { wptr = wv; outbase = 294912; erow0 = e0 - 9216; }

  const int tid  = threadIdx.x;
  const int lane = tid & 63;
  const int w    = tid >> 6;     // wave 0..3

  // MFMA fragment addressing (wave quadrant of the 32x32 tile)
  const int wm   = w >> 1, wn = w & 1;
  const int arow = wm * 16 + (lane & 15);   // batch row
  const int brow = wn * 16 + (lane & 15);   // weight row (within tile)
  const int kg   = (lane >> 4) * 8;         // k-group offset
  const int axor = (arow & 7) << 3;
  const int bxor = (brow & 7) << 3;

  f32x4 acc = {0.f, 0.f, 0.f, 0.f};
  f32x4 xs0[4], ws0[4], xs1[4], ws1[4];

  ISSUE_LOADS(xs0, ws0, 0);
  ISSUE_LOADS(xs1, ws1, 1);

  for (int c = 0; c < NCHUNK; c += 2) {
    CVT_WRITE(xs0, ws0, 0);
    if (c + 2 < NCHUNK) ISSUE_LOADS(xs0, ws0, c + 2);
    __syncthreads();
    MFMA_STEP(0);

    CVT_WRITE(xs1, ws1, 1);
    if (c + 3 < NCHUNK) ISSUE_LOADS(xs1, ws1, c + 3);
    __syncthreads();
    MFMA_STEP(1);
  }

  // C/D layout: col = lane&15 (weight row n), row = (lane>>4)*4+r (batch b)
  const int nloc = wn * 16 + (lane & 15);
  const int mb0  = wm * 16 + (lane >> 4) * 4;
  if (WRITE_MODE == 0) {
    // disjoint partial tile: ws[(kslice*NTILE + tile)*1024 + b*32 + n]
    float* p = ws_out + ((size_t)(kslice * NTILE + tile)) * 1024;
    #pragma unroll
    for (int r = 0; r < 4; ++r)
      p[(mb0 + r) * 32 + nloc] = acc[r];
  } else {
    const int er    = erow0 + nloc;
    const int obase = outbase + (er >> 7) * (32 * 128) + (er & 127);
    #pragma unroll
    for (int r = 0; r < 4; ++r)
      atomicAdd(&out[obase + (size_t)(mb0 + r) * 128], acc[r]);
  }
}

// Reduce 8 k-slice partials per tile and scatter to head-layout output.
__global__ __launch_bounds__(256) void qkv_reduce(
    const float* __restrict__ ws, float* __restrict__ out)
{
  const int tile = blockIdx.x;
  const int e0   = tile * BN;
  int outbase, erow0;
  if (e0 < 8192)      { outbase = 0;      erow0 = e0; }
  else if (e0 < 9216) { outbase = 262144; erow0 = e0 - 8192; }
  else                { outbase = 294912; erow0 = e0 - 9216; }

  #pragma unroll
  for (int t = 0; t < 4; ++t) {
    const int idx = threadIdx.x + t * 256;   // b*32 + n
    float s = 0.f;
    #pragma unroll
    for (int sl = 0; sl < SPLITK; ++sl)
      s += ws[((size_t)(sl * NTILE + tile)) * 1024 + idx];
    const int b  = idx >> 5;
    const int n  = idx & 31;
    const int er = erow0 + n;
    out[outbase + (er >> 7) * (32 * 128) + b * 128 + (er & 127)] = s;
  }
}

extern "C" void kernel_launch(void* const* d_in, const int* in_sizes, int n_in,
                              void* d_out, int out_size, void* d_ws, size_t ws_size,
                              hipStream_t stream) {
  const float* x  = (const float*)d_in[0];
  const float* wq = (const float*)d_in[1];
  const float* wk = (const float*)d_in[2];
  const float* wv = (const float*)d_in[3];
  float* out = (float*)d_out;
  const size_t need = (size_t)SPLITK * NTILE * 1024 * sizeof(float);
  if (ws_size >= need) {
    qkv_gemm<0><<<dim3(NTILE * SPLITK), dim3(256), 0, stream>>>(
        x, wq, wk, wv, (float*)d_ws, out);
    qkv_reduce<<<dim3(NTILE), dim3(256), 0, stream>>>((const float*)d_ws, out);
  } else {
    hipMemsetAsync(out, 0, (size_t)out_size * sizeof(float), stream);
    qkv_gemm<1><<<dim3(NTILE * SPLITK), dim3(256), 0, stream>>>(
        x, wq, wk, wv, nullptr, out);
  }
}

// Round 4
// 92.400 us; speedup vs baseline: 3.0062x; 3.0062x over previous
//
#include <hip/hip_runtime.h>

#define D_DIM 8192
#define SPLITK 16
#define KS (D_DIM / SPLITK)   // 512 per slice
#define NITER (KS / 32)       // 16 k-chunks of 32
#define NGROUP 320            // 32-weight-row groups (q:0-255, k:256-287, v:288-319)
#define GPB 4                 // groups per block = 1 per wave

typedef float f32x4 __attribute__((ext_vector_type(4)));
typedef short s16x8 __attribute__((ext_vector_type(8)));

__device__ __forceinline__ unsigned short f2bf(float f) {
  union { float f; unsigned u; } v; v.f = f;
  return (unsigned short)((v.u + 0x7FFFu + ((v.u >> 16) & 1u)) >> 16);
}

__device__ __forceinline__ s16x8 pack_bf16(f32x4 lo, f32x4 hi) {
  s16x8 r;
  r[0] = (short)f2bf(lo[0]); r[1] = (short)f2bf(lo[1]);
  r[2] = (short)f2bf(lo[2]); r[3] = (short)f2bf(lo[3]);
  r[4] = (short)f2bf(hi[0]); r[5] = (short)f2bf(hi[1]);
  r[6] = (short)f2bf(hi[2]); r[7] = (short)f2bf(hi[3]);
  return r;
}

// No LDS, no barriers: each wave computes a 32(batch)x32(weight-row) tile for
// one K-slice, loading MFMA fragments directly from global fp32 and converting
// to bf16 in registers. 8 independent dwordx4 loads per lane per K=32 chunk.
template <int MODE>  // 0 = workspace partials, 1 = atomicAdd fallback
__global__ __launch_bounds__(256, 4) void qkv_gemm(
    const float* __restrict__ x, const float* __restrict__ wq,
    const float* __restrict__ wk, const float* __restrict__ wv,
    float* __restrict__ wsb, float* __restrict__ out)
{
  const int bid   = blockIdx.x;
  const int ksl   = bid & (SPLITK - 1);
  const int gblk  = bid >> 4;                 // log2(SPLITK)
  const int w     = threadIdx.x >> 6;
  const int lane  = threadIdx.x & 63;
  const int group = gblk * GPB + w;           // 0..319
  const int n0    = group * 32;               // global weight row base

  const float* wptr; int erow0, outbase;
  if (n0 < 8192)      { wptr = wq; outbase = 0;      erow0 = n0; }
  else if (n0 < 9216) { wptr = wk; outbase = 262144; erow0 = n0 - 8192; }
  else                { wptr = wv; outbase = 294912; erow0 = n0 - 9216; }

  const int la = lane & 15;          // row within 16-tile
  const int kg = (lane >> 4) * 8;    // k-subgroup offset
  const size_t kbase = (size_t)ksl * KS;

  const float* ax0 = x    + (size_t)la * D_DIM + kbase + kg;            // batch 0-15
  const float* ax1 = ax0  + (size_t)16 * D_DIM;                         // batch 16-31
  const float* bw0 = wptr + (size_t)(erow0 + la) * D_DIM + kbase + kg;  // n-tile 0
  const float* bw1 = bw0  + (size_t)16 * D_DIM;                         // n-tile 1

  f32x4 acc00 = {0.f,0.f,0.f,0.f}, acc01 = {0.f,0.f,0.f,0.f};
  f32x4 acc10 = {0.f,0.f,0.f,0.f}, acc11 = {0.f,0.f,0.f,0.f};

  #pragma unroll 2
  for (int it = 0; it < NITER; ++it) {
    const int ko = it * 32;
    f32x4 a0l = *reinterpret_cast<const f32x4*>(ax0 + ko);
    f32x4 a0h = *reinterpret_cast<const f32x4*>(ax0 + ko + 4);
    f32x4 a1l = *reinterpret_cast<const f32x4*>(ax1 + ko);
    f32x4 a1h = *reinterpret_cast<const f32x4*>(ax1 + ko + 4);
    f32x4 b0l = *reinterpret_cast<const f32x4*>(bw0 + ko);
    f32x4 b0h = *reinterpret_cast<const f32x4*>(bw0 + ko + 4);
    f32x4 b1l = *reinterpret_cast<const f32x4*>(bw1 + ko);
    f32x4 b1h = *reinterpret_cast<const f32x4*>(bw1 + ko + 4);

    s16x8 fa0 = pack_bf16(a0l, a0h);
    s16x8 fa1 = pack_bf16(a1l, a1h);
    s16x8 fb0 = pack_bf16(b0l, b0h);
    s16x8 fb1 = pack_bf16(b1l, b1h);

    acc00 = __builtin_amdgcn_mfma_f32_16x16x32_bf16(fa0, fb0, acc00, 0, 0, 0);
    acc10 = __builtin_amdgcn_mfma_f32_16x16x32_bf16(fa1, fb0, acc10, 0, 0, 0);
    acc01 = __builtin_amdgcn_mfma_f32_16x16x32_bf16(fa0, fb1, acc01, 0, 0, 0);
    acc11 = __builtin_amdgcn_mfma_f32_16x16x32_bf16(fa1, fb1, acc11, 0, 0, 0);
  }

  // C/D layout (verified R1-R3): col = lane&15 = n within tile, row = (lane>>4)*4+r = batch
  const int m0 = (lane >> 4) * 4;
  if (MODE == 0) {
    float* p = wsb + ((size_t)(ksl * NGROUP + group)) * 1024;  // [b][n] 32x32
    #pragma unroll
    for (int r = 0; r < 4; ++r) {
      p[(m0 + r) * 32 + la]           = acc00[r];
      p[(m0 + r) * 32 + 16 + la]      = acc01[r];
      p[(16 + m0 + r) * 32 + la]      = acc10[r];
      p[(16 + m0 + r) * 32 + 16 + la] = acc11[r];
    }
  } else {
    #pragma unroll
    for (int ni = 0; ni < 2; ++ni) {
      const int er    = erow0 + ni * 16 + la;
      const int obase = outbase + (er >> 7) * 4096 + (er & 127);
      f32x4 ac0 = ni ? acc01 : acc00;
      f32x4 ac1 = ni ? acc11 : acc10;
      #pragma unroll
      for (int r = 0; r < 4; ++r) {
        atomicAdd(&out[obase + (size_t)(m0 + r) * 128],      ac0[r]);
        atomicAdd(&out[obase + (size_t)(16 + m0 + r) * 128], ac1[r]);
      }
    }
  }
}

// Sum SPLITK partial tiles per group and scatter to head-layout output.
__global__ __launch_bounds__(256) void qkv_reduce(
    const float* __restrict__ ws, float* __restrict__ out)
{
  const int group = blockIdx.x;
  #pragma unroll
  for (int t = 0; t < 4; ++t) {
    const int idx = threadIdx.x + t * 256;   // b*32 + n
    float s = 0.f;
    #pragma unroll
    for (int sl = 0; sl < SPLITK; ++sl)
      s += ws[((size_t)(sl * NGROUP + group)) * 1024 + idx];
    const int b = idx >> 5;
    const int n = idx & 31;
    const int e = group * 32 + n;
    int outbase, er;
    if (e < 8192)      { outbase = 0;      er = e; }
    else if (e < 9216) { outbase = 262144; er = e - 8192; }
    else               { outbase = 294912; er = e - 9216; }
    out[outbase + (er >> 7) * 4096 + b * 128 + (er & 127)] = s;
  }
}

extern "C" void kernel_launch(void* const* d_in, const int* in_sizes, int n_in,
                              void* d_out, int out_size, void* d_ws, size_t ws_size,
                              hipStream_t stream) {
  const float* x  = (const float*)d_in[0];
  const float* wq = (const float*)d_in[1];
  const float* wk = (const float*)d_in[2];
  const float* wv = (const float*)d_in[3];
  float* out = (float*)d_out;
  const size_t need = (size_t)SPLITK * NGROUP * 1024 * sizeof(float);
  if (ws_size >= need) {
    qkv_gemm<0><<<dim3(NGROUP / GPB * SPLITK), dim3(256), 0, stream>>>(
        x, wq, wk, wv, (float*)d_ws, out);
    qkv_reduce<<<dim3(NGROUP), dim3(256), 0, stream>>>((const float*)d_ws, out);
  } else {
    hipMemsetAsync(out, 0, (size_t)out_size * sizeof(float), stream);
    qkv_gemm<1><<<dim3(NGROUP / GPB * SPLITK), dim3(256), 0, stream>>>(
        x, wq, wk, wv, nullptr, out);
  }
}